// Round 6
// baseline (4584.316 us; speedup 1.0000x reference)
//
#include <hip/hip_runtime.h>
#include <math.h>

#define TT 35
#define BB 64
#define EMB 1500
#define HID 1500
#define VOCAB 10000
#define KT 3072          // layer1 K: 2*HID padded
#define KH 1536          // layer0 h-part K padded
#define KLP 1504         // HID padded to x32 (logits K)
#define NBLK 158         // vocab 64-col blocks
#define MROWS 2240
#define MPAD 2304
#define LBLK 94
#define ZXN 6000
#define FORGET_BIAS 1.0f
// lstm job geometry (all jobs: 4 k-groups, chunks of 32)
#define NCH0 12          // layer0-h: K=1536, kgK=384
#define KG0 384
#define NCH1M 18         // layer1 main: K in [0,2304), kgK=576
#define KG1M 576
#define NCH1T 6          // layer1 tail: K in [2304,3072), kgK=192
#define KG1T 192
#define KW1T 2304

typedef __bf16 bf16x8 __attribute__((ext_vector_type(8)));
typedef float f32x4 __attribute__((ext_vector_type(4)));

__device__ __forceinline__ unsigned short f2bf(float f) {
    unsigned int u = __builtin_bit_cast(unsigned int, f);
    u += 0x7fffu + ((u >> 16) & 1u);           // RNE
    return (unsigned short)(u >> 16);
}
__device__ __forceinline__ float bf2f(unsigned short u) {
    unsigned int v = ((unsigned int)u) << 16;
    return __builtin_bit_cast(float, v);
}
__device__ __forceinline__ float sigmoidf_(float x) { return 1.0f / (1.0f + expf(-x)); }

#define GLOAD_LDS16(gp, lp) __builtin_amdgcn_global_load_lds( \
    (const __attribute__((address_space(1))) void*)(gp),      \
    (__attribute__((address_space(3))) void*)(lp), 16, 0, 0)

// ---- W (K x N fp32) -> WT (N x KP bf16), zero-fill k in [K,KP) ----
__global__ __launch_bounds__(256) void convT(const float* __restrict__ W,
                                             unsigned short* __restrict__ WT,
                                             int K, int N, int KP) {
    __shared__ float tile[32][33];
    int tx = threadIdx.x, ty = threadIdx.y;    // 32 x 8
    int n0 = blockIdx.x * 32, k0 = blockIdx.y * 32;
#pragma unroll
    for (int i = 0; i < 4; ++i) {
        int k = k0 + ty + 8 * i, n = n0 + tx;
        tile[ty + 8 * i][tx] = (k < K && n < N) ? W[(size_t)k * N + n] : 0.f;
    }
    __syncthreads();
#pragma unroll
    for (int i = 0; i < 4; ++i) {
        int n = n0 + ty + 8 * i, k = k0 + tx;
        if (n < N) WT[(size_t)n * KP + k] = f2bf(tile[tx][ty + 8 * i]);
    }
}

// ---- embedding gather -> bf16 A_emb rows (stride KH, cols 0..1499) ----
__global__ __launch_bounds__(256) void embed_kernel(const int* __restrict__ x,
                                                    const float* __restrict__ emb,
                                                    unsigned short* __restrict__ Ae) {
    int tok = blockIdx.x;
    int v = x[tok];
    const float* src = emb + (size_t)v * EMB;
    unsigned short* dst = Ae + (size_t)tok * KH;
    for (int i = threadIdx.x; i < EMB; i += 256) dst[i] = f2bf(src[i]);
}

// ====================== lstm building blocks ======================
// One GEMM "job": 64 rows x 16 cols x (4 kg x nch chunks of 32 K).
// Counted-vmcnt 4-buffer pipeline (proven round 4). LDS bufs at 32KB stride.
__device__ __forceinline__ void run_job(const unsigned short* __restrict__ A, int As,
                                        const unsigned short* __restrict__ W, int Ws,
                                        int kwin, int kgK, int nch, int nb,
                                        unsigned char* smem,
                                        int mt, int kg, int lane, int l16,
                                        int sp, int swz,
                                        f32x4& acc0, f32x4& acc1, f32x4& acc2, f32x4& acc3) {
    int rr = lane >> 2;
    int kbase = kwin + kg * kgK;
    int q0 = mt * 2, q1 = q0 + 1;
    const unsigned short* gp[2];
    int ldsoff[2];
#pragma unroll
    for (int ii = 0; ii < 2; ++ii) {
        int q = ii ? q1 : q0;
        if (q < 4) {                            // A rows 16q+rr
            gp[ii] = A + (size_t)(16 * q + rr) * As + kbase + sp * 8;
        } else {                                // B: gate g=q-4, col rr
            int ci = nb * 16 + rr; if (ci > HID - 1) ci = HID - 1;
            gp[ii] = W + (size_t)((q - 4) * HID + ci) * Ws + kbase + sp * 8;
        }
        ldsoff[ii] = ((q >> 2) * 4 + kg) * 4096 + (q & 3) * 1024;    // + buf*32768
    }
    int aoff = kg * 4096 + (mt * 16 + l16) * 64 + swz;
    int boff = (4 + kg) * 4096 + l16 * 64 + swz;

    acc0 = (f32x4){0.f, 0.f, 0.f, 0.f}; acc1 = acc0; acc2 = acc0; acc3 = acc0;

    // prologue: stage chunks 0..2 into bufs 0..2
#pragma unroll
    for (int ci = 0; ci < 3; ++ci) {
        GLOAD_LDS16(gp[0] + ci * 32, smem + ci * 32768 + ldsoff[0]);
        GLOAD_LDS16(gp[1] + ci * 32, smem + ci * 32768 + ldsoff[1]);
    }
    for (int c = 0; c < nch; ++c) {
        asm volatile("s_waitcnt vmcnt(4)" ::: "memory");   // my stage(c) landed
        __builtin_amdgcn_sched_barrier(0);
        __builtin_amdgcn_s_barrier();
        int cs = (c + 3 < nch) ? (c + 3) : (nch - 1);      // dummy tail re-stage
        int bs_ = (c + 3) & 3;
        GLOAD_LDS16(gp[0] + cs * 32, smem + bs_ * 32768 + ldsoff[0]);
        GLOAD_LDS16(gp[1] + cs * 32, smem + bs_ * 32768 + ldsoff[1]);
        const unsigned char* base = smem + (c & 3) * 32768;
        bf16x8 a  = *(const bf16x8*)(base + aoff);
        bf16x8 b0 = *(const bf16x8*)(base + boff);
        bf16x8 b1 = *(const bf16x8*)(base + boff + 1024);
        bf16x8 b2 = *(const bf16x8*)(base + boff + 2048);
        bf16x8 b3 = *(const bf16x8*)(base + boff + 3072);
        __builtin_amdgcn_s_setprio(1);
        acc0 = __builtin_amdgcn_mfma_f32_16x16x32_bf16(a, b0, acc0, 0, 0, 0);
        acc1 = __builtin_amdgcn_mfma_f32_16x16x32_bf16(a, b1, acc1, 0, 0, 0);
        acc2 = __builtin_amdgcn_mfma_f32_16x16x32_bf16(a, b2, acc2, 0, 0, 0);
        acc3 = __builtin_amdgcn_mfma_f32_16x16x32_bf16(a, b3, acc3, 0, 0, 0);
        __builtin_amdgcn_s_setprio(0);
    }
    asm volatile("s_waitcnt vmcnt(0)" ::: "memory");        // drain before smem reuse
    __builtin_amdgcn_sched_barrier(0);
    __syncthreads();
}

// k-group reduction through LDS overlay; kg==0 waves end with the full sum.
__device__ __forceinline__ void kg_reduce(unsigned char* smem, int kg, int mt, int lane,
                                          f32x4& acc0, f32x4& acc1, f32x4& acc2, f32x4& acc3) {
    float* red = (float*)smem;                  // [12 waves][64 lanes][16]
    if (kg > 0) {
        int w = (kg - 1) * 4 + mt;
#pragma unroll
        for (int r = 0; r < 4; ++r) {
            red[(w * 64 + lane) * 16 + r]      = acc0[r];
            red[(w * 64 + lane) * 16 + 4 + r]  = acc1[r];
            red[(w * 64 + lane) * 16 + 8 + r]  = acc2[r];
            red[(w * 64 + lane) * 16 + 12 + r] = acc3[r];
        }
    }
    __syncthreads();
    if (kg == 0) {
#pragma unroll
        for (int k2 = 0; k2 < 3; ++k2) {
            int w = k2 * 4 + mt;
#pragma unroll
            for (int r = 0; r < 4; ++r) {
                acc0[r] += red[(w * 64 + lane) * 16 + r];
                acc1[r] += red[(w * 64 + lane) * 16 + 4 + r];
                acc2[r] += red[(w * 64 + lane) * 16 + 8 + r];
                acc3[r] += red[(w * 64 + lane) * 16 + 12 + r];
            }
        }
    }
    __syncthreads();                            // red safe to overwrite after this
}

// ---- fused LSTM pair step, balanced 18/18 split ----
// B-blocks (0..93):   layer1[k-1] cols cb, K in [0,2304)   (18 chunks) -> partial
// A-blocks (94..187): layer0-h[k] cols cb  (12 chunks, full epilogue w/ Zx)
//                     then layer1[k-1] cols cb, K in [2304,3072) (6 chunks) -> partial
// Last finisher per cb combines both layer1 partials and runs the layer1 epilogue
// (canonical threadfence + syncthreads + tid0 atomicAdd protocol; all 188 blocks
// co-resident at 1 block/CU so no ordering assumption is needed, and there is no
// spinning -> deadlock-free). Finisher resets the flag for the next launch.
__global__ __launch_bounds__(1024) void lstm_pair(
        const unsigned short* __restrict__ A_0, const unsigned short* __restrict__ WT_0,
        const float* __restrict__ bias_0, float* __restrict__ cst_0,
        unsigned short* __restrict__ d1_0, int s1_0, unsigned short* __restrict__ d2_0, int s2_0,
        const unsigned short* __restrict__ zx_0,
        const unsigned short* __restrict__ A_1, const unsigned short* __restrict__ WT_1,
        const float* __restrict__ bias_1, float* __restrict__ cst_1,
        unsigned short* __restrict__ d1_1, int s1_1, unsigned short* __restrict__ d2_1, int s2_1,
        float* __restrict__ zpart, int* __restrict__ zflag) {
    __shared__ __align__(16) unsigned char smem[131072];
    __shared__ int oldflag;

    int tid = threadIdx.x;
    int wv = tid >> 6, lane = tid & 63;
    int mt = wv & 3, kg = wv >> 2;
    int quad = lane >> 4, l16 = lane & 15;
    int rr = lane >> 2, p = lane & 3;
    int sp = p ^ (rr & 3) ^ ((rr >> 2) & 3);                 // stage-side pre-swizzle
    int swz = (quad ^ (l16 & 3) ^ ((l16 >> 2) & 3)) * 16;    // matching read swizzle

    bool isA = (blockIdx.x >= LBLK);
    int cb = isA ? (int)blockIdx.x - LBLK : (int)blockIdx.x;
    bool doL1 = (A_1 != nullptr);
    f32x4 acc0, acc1, acc2, acc3;

    if (isA) {
        if (A_0) {
            run_job(A_0, KH, WT_0, KH, 0, KG0, NCH0, cb, smem,
                    mt, kg, lane, l16, sp, swz, acc0, acc1, acc2, acc3);
            kg_reduce(smem, kg, mt, lane, acc0, acc1, acc2, acc3);
            if (kg == 0) {
                int col = cb * 16 + l16;
                if (col < HID) {
                    float bi = bias_0[col], bj = bias_0[HID + col];
                    float bf_ = bias_0[2 * HID + col], bo = bias_0[3 * HID + col];
#pragma unroll
                    for (int r = 0; r < 4; ++r) {
                        int row = mt * 16 + quad * 4 + r;
                        const unsigned short* zr = zx_0 + (size_t)row * ZXN;
                        float zi = acc0[r] + bi + bf2f(zr[col]);
                        float zj = acc1[r] + bj + bf2f(zr[HID + col]);
                        float zf = acc2[r] + bf_ + bf2f(zr[2 * HID + col]);
                        float zo = acc3[r] + bo + bf2f(zr[3 * HID + col]);
                        int ci = row * HID + col;
                        float cn = cst_0[ci] * sigmoidf_(zf + FORGET_BIAS) + sigmoidf_(zi) * tanhf(zj);
                        float hn = tanhf(cn) * sigmoidf_(zo);
                        cst_0[ci] = cn;
                        unsigned short hb = f2bf(hn);
                        d1_0[(size_t)row * s1_0 + col] = hb;
                        d2_0[(size_t)row * s2_0 + col] = hb;
                    }
                }
            }
        }
        if (!doL1) return;
        run_job(A_1, KT, WT_1, KT, KW1T, KG1T, NCH1T, cb, smem,
                mt, kg, lane, l16, sp, swz, acc0, acc1, acc2, acc3);
        kg_reduce(smem, kg, mt, lane, acc0, acc1, acc2, acc3);
    } else {
        if (!doL1) return;
        run_job(A_1, KT, WT_1, KT, 0, KG1M, NCH1M, cb, smem,
                mt, kg, lane, l16, sp, swz, acc0, acc1, acc2, acc3);
        kg_reduce(smem, kg, mt, lane, acc0, acc1, acc2, acc3);
    }

    // ---- split-K combine: write own partial, last finisher does epilogue ----
    int half = isA ? 1 : 0;
    float* zp = zpart + ((size_t)cb * 2 + half) * 4096;      // [4 waves][64 lanes][16]
    if (kg == 0) {
#pragma unroll
        for (int r = 0; r < 4; ++r) {
            zp[(mt * 64 + lane) * 16 + r]      = acc0[r];
            zp[(mt * 64 + lane) * 16 + 4 + r]  = acc1[r];
            zp[(mt * 64 + lane) * 16 + 8 + r]  = acc2[r];
            zp[(mt * 64 + lane) * 16 + 12 + r] = acc3[r];
        }
    }
    __threadfence();
    __syncthreads();
    if (tid == 0) oldflag = atomicAdd(&zflag[cb], 1);
    __syncthreads();
    if (oldflag == 1) {                         // block-uniform branch
        __threadfence();
        if (kg == 0) {
            const float* zq = zpart + ((size_t)cb * 2 + (half ^ 1)) * 4096;
#pragma unroll
            for (int r = 0; r < 4; ++r) {
                acc0[r] += zq[(mt * 64 + lane) * 16 + r];
                acc1[r] += zq[(mt * 64 + lane) * 16 + 4 + r];
                acc2[r] += zq[(mt * 64 + lane) * 16 + 8 + r];
                acc3[r] += zq[(mt * 64 + lane) * 16 + 12 + r];
            }
            int col = cb * 16 + l16;
            if (col < HID) {
                float bi = bias_1[col], bj = bias_1[HID + col];
                float bf_ = bias_1[2 * HID + col], bo = bias_1[3 * HID + col];
#pragma unroll
                for (int r = 0; r < 4; ++r) {
                    int row = mt * 16 + quad * 4 + r;
                    float zi = acc0[r] + bi;
                    float zj = acc1[r] + bj;
                    float zf = acc2[r] + bf_;
                    float zo = acc3[r] + bo;
                    int ci = row * HID + col;
                    float cn = cst_1[ci] * sigmoidf_(zf + FORGET_BIAS) + sigmoidf_(zi) * tanhf(zj);
                    float hn = tanhf(cn) * sigmoidf_(zo);
                    cst_1[ci] = cn;
                    unsigned short hb = f2bf(hn);
                    d1_1[(size_t)row * s1_1 + col] = hb;
                    if (d2_1) d2_1[(size_t)row * s2_1 + col] = hb;
                }
            }
        }
        __syncthreads();
        if (tid == 0) zflag[cb] = 0;            // reset for next launch
    }
}

// ---- batched x-part GEMM for layer0: Zx = A_emb @ W0x^T, bf16 out ----
// rectangle XCD partition; counted-vmcnt 4-buf pipeline; fixed LDS swizzle.
__global__ __launch_bounds__(256) void zx_gemm(const unsigned short* __restrict__ A,   // MPAD x KH
                                               const unsigned short* __restrict__ WT,  // 6000 x KH
                                               unsigned short* __restrict__ Zx) {      // MPAD x ZXN
    __shared__ __align__(16) unsigned char smem[65536];
    int orig = blockIdx.x;
    int xcd = orig & 7, j = orig >> 3;          // j < 108
    int mb, bn;
    if (xcd < 7) { bn = xcd * 6 + j % 6; mb = j / 6; }
    else { if (j >= 90) return; bn = 42 + j % 5; mb = j / 5; }
    int n0 = bn * 128;

    int tid = threadIdx.x;
    int wv = tid >> 6, lane = tid & 63;
    int wr = wv >> 1, wc = wv & 1;
    int quad = lane >> 4, l16 = lane & 15;
    int rr = lane >> 2;
    int ks = (lane & 3) ^ (rr & 3) ^ ((rr >> 2) & 3);
    const unsigned short* gA[2]; const unsigned short* gB[2];
    int ldsA[2], ldsB[2];
#pragma unroll
    for (int i = 0; i < 2; ++i) {
        int r16 = wv * 2 + i;
        int ra = mb * 128 + r16 * 16 + rr;
        gA[i] = A + (size_t)ra * KH + ks * 8;
        ldsA[i] = r16 * 1024;
        int rb = n0 + r16 * 16 + rr;
        if (rb > 5999) rb = 5999;
        gB[i] = WT + (size_t)rb * KH + ks * 8;
        ldsB[i] = 8192 + r16 * 1024;
    }
    int sw16 = (quad ^ (l16 & 3) ^ ((l16 >> 2) & 3)) * 16;
    int aoff[4], boff[4];
#pragma unroll
    for (int f = 0; f < 4; ++f) {
        aoff[f] = (wr * 64 + f * 16 + l16) * 64 + sw16;
        boff[f] = 8192 + (wc * 64 + f * 16 + l16) * 64 + sw16;
    }
    f32x4 acc[4][4];
#pragma unroll
    for (int i = 0; i < 4; ++i)
#pragma unroll
        for (int jj = 0; jj < 4; ++jj) acc[i][jj] = (f32x4){0.f, 0.f, 0.f, 0.f};

    const int NCHZ = KH / 32;                   // 48
#pragma unroll
    for (int ci = 0; ci < 3; ++ci)
#pragma unroll
        for (int i = 0; i < 2; ++i) {
            GLOAD_LDS16(gA[i] + ci * 32, smem + ci * 16384 + ldsA[i]);
            GLOAD_LDS16(gB[i] + ci * 32, smem + ci * 16384 + ldsB[i]);
        }
    for (int c = 0; c < NCHZ; ++c) {
        asm volatile("s_waitcnt vmcnt(8)" ::: "memory");
        __builtin_amdgcn_sched_barrier(0);
        __builtin_amdgcn_s_barrier();
        int cs = (c + 3 < NCHZ) ? (c + 3) : (NCHZ - 1);
        int ob = ((c + 3) & 3) * 16384;
#pragma unroll
        for (int i = 0; i < 2; ++i) {
            GLOAD_LDS16(gA[i] + cs * 32, smem + ob + ldsA[i]);
            GLOAD_LDS16(gB[i] + cs * 32, smem + ob + ldsB[i]);
        }
        const unsigned char* base = smem + (c & 3) * 16384;
        bf16x8 a[4], b[4];
#pragma unroll
        for (int f = 0; f < 4; ++f) {
            a[f] = *(const bf16x8*)(base + aoff[f]);
            b[f] = *(const bf16x8*)(base + boff[f]);
        }
        __builtin_amdgcn_s_setprio(1);
#pragma unroll
        for (int ar = 0; ar < 4; ++ar)
#pragma unroll
            for (int cbv = 0; cbv < 4; ++cbv)
                acc[ar][cbv] = __builtin_amdgcn_mfma_f32_16x16x32_bf16(a[ar], b[cbv], acc[ar][cbv], 0, 0, 0);
        __builtin_amdgcn_s_setprio(0);
    }
    asm volatile("s_waitcnt vmcnt(0)" ::: "memory");
    __builtin_amdgcn_sched_barrier(0);
    __syncthreads();

#pragma unroll
    for (int ar = 0; ar < 4; ++ar)
#pragma unroll
        for (int cbv = 0; cbv < 4; ++cbv)
#pragma unroll
            for (int r2 = 0; r2 < 4; ++r2) {
                int row = mb * 128 + wr * 64 + ar * 16 + quad * 4 + r2;
                int col = n0 + wc * 64 + cbv * 16 + l16;
                if (col < ZXN) Zx[(size_t)row * ZXN + col] = f2bf(acc[ar][cbv][r2]);
            }
}

// ---- logits + flash fold; rectangle XCD partition + counted-vmcnt pipeline ----
__global__ __launch_bounds__(256) void logits_fold(const unsigned short* __restrict__ A,   // MPAD x KLP
                                                   const unsigned short* __restrict__ WT,  // 10000 x KLP
                                                   const float* __restrict__ sb,
                                                   const int* __restrict__ y,
                                                   float2* __restrict__ partials,          // [2240][NBLK]
                                                   float* __restrict__ tgtlog) {           // [2240]
    __shared__ __align__(16) unsigned char smem[65536];

    int orig = blockIdx.x;
    int xcd = orig & 7, j = orig >> 3;          // j < 180
    int mb, bn;
    if (xcd < 7) { bn = xcd * 10 + j % 10; mb = j / 10; }
    else { if (j >= 162) return; bn = 70 + j % 9; mb = j / 9; }
    int n0 = bn * 128;

    int tid = threadIdx.x;
    int wv = tid >> 6, lane = tid & 63;
    int wr = wv >> 1, wc = wv & 1;
    int quad = lane >> 4, l16 = lane & 15;

    int rr = lane >> 2;
    int ks = (lane & 3) ^ (rr & 3) ^ ((rr >> 2) & 3);
    const unsigned short* gA[2]; const unsigned short* gB[2];
    int ldsA[2], ldsB[2];
#pragma unroll
    for (int i = 0; i < 2; ++i) {
        int r16 = wv * 2 + i;
        int ra = mb * 128 + r16 * 16 + rr;
        gA[i] = A + (size_t)ra * KLP + ks * 8;
        ldsA[i] = r16 * 1024;
        int rb = n0 + r16 * 16 + rr;
        if (rb > VOCAB - 1) rb = VOCAB - 1;
        gB[i] = WT + (size_t)rb * KLP + ks * 8;
        ldsB[i] = 8192 + r16 * 1024;
    }

    int sw16 = (quad ^ (l16 & 3) ^ ((l16 >> 2) & 3)) * 16;
    int aoff[4], boff[4];
#pragma unroll
    for (int f = 0; f < 4; ++f) {
        aoff[f] = (wr * 64 + f * 16 + l16) * 64 + sw16;
        boff[f] = 8192 + (wc * 64 + f * 16 + l16) * 64 + sw16;
    }

    f32x4 acc[4][4];
#pragma unroll
    for (int i = 0; i < 4; ++i)
#pragma unroll
        for (int jj = 0; jj < 4; ++jj) acc[i][jj] = (f32x4){0.f, 0.f, 0.f, 0.f};

    const int NCHL = KLP / 32;                  // 47
#pragma unroll
    for (int ci = 0; ci < 3; ++ci)
#pragma unroll
        for (int i = 0; i < 2; ++i) {
            GLOAD_LDS16(gA[i] + ci * 32, smem + ci * 16384 + ldsA[i]);
            GLOAD_LDS16(gB[i] + ci * 32, smem + ci * 16384 + ldsB[i]);
        }
    for (int c = 0; c < NCHL; ++c) {
        asm volatile("s_waitcnt vmcnt(8)" ::: "memory");
        __builtin_amdgcn_sched_barrier(0);
        __builtin_amdgcn_s_barrier();
        int cs = (c + 3 < NCHL) ? (c + 3) : (NCHL - 1);
        int ob = ((c + 3) & 3) * 16384;
#pragma unroll
        for (int i = 0; i < 2; ++i) {
            GLOAD_LDS16(gA[i] + cs * 32, smem + ob + ldsA[i]);
            GLOAD_LDS16(gB[i] + cs * 32, smem + ob + ldsB[i]);
        }
        const unsigned char* base = smem + (c & 3) * 16384;
        bf16x8 a[4], b[4];
#pragma unroll
        for (int f = 0; f < 4; ++f) {
            a[f] = *(const bf16x8*)(base + aoff[f]);
            b[f] = *(const bf16x8*)(base + boff[f]);
        }
        __builtin_amdgcn_s_setprio(1);
#pragma unroll
        for (int ar = 0; ar < 4; ++ar)
#pragma unroll
            for (int cbv = 0; cbv < 4; ++cbv)
                acc[ar][cbv] = __builtin_amdgcn_mfma_f32_16x16x32_bf16(a[ar], b[cbv], acc[ar][cbv], 0, 0, 0);
        __builtin_amdgcn_s_setprio(0);
    }
    asm volatile("s_waitcnt vmcnt(0)" ::: "memory");
    __builtin_amdgcn_sched_barrier(0);
    __syncthreads();

    int colv[4]; float bs[4];
#pragma unroll
    for (int cbv = 0; cbv < 4; ++cbv) {
        int c = n0 + wc * 64 + cbv * 16 + l16;
        colv[cbv] = c;
        int cc = (c < VOCAB) ? c : (VOCAB - 1);
        bs[cbv] = sb[cc];
    }
    int nb2 = bn * 2 + wc;
#pragma unroll
    for (int ar = 0; ar < 4; ++ar) {
#pragma unroll
        for (int r2 = 0; r2 < 4; ++r2) {
            float v0 = acc[ar][0][r2] + bs[0];
            float v1 = acc[ar][1][r2] + bs[1];
            float v2 = acc[ar][2][r2] + bs[2];
            float v3 = acc[ar][3][r2] + bs[3];
            if (colv[0] >= VOCAB) v0 = -1e30f;
            if (colv[1] >= VOCAB) v1 = -1e30f;
            if (colv[2] >= VOCAB) v2 = -1e30f;
            if (colv[3] >= VOCAB) v3 = -1e30f;
            int row = mb * 128 + wr * 64 + ar * 16 + quad * 4 + r2;
            int t = y[row < MROWS ? row : 0];
            float tv = -1e30f;
            if (colv[0] == t) tv = v0;
            if (colv[1] == t) tv = v1;
            if (colv[2] == t) tv = v2;
            if (colv[3] == t) tv = v3;
            float mx = fmaxf(fmaxf(v0, v1), fmaxf(v2, v3));
#pragma unroll
            for (int d = 1; d < 16; d <<= 1) mx = fmaxf(mx, __shfl_xor(mx, d, 64));
            float sum = expf(v0 - mx) + expf(v1 - mx) + expf(v2 - mx) + expf(v3 - mx);
#pragma unroll
            for (int d = 1; d < 16; d <<= 1) sum += __shfl_xor(sum, d, 64);
#pragma unroll
            for (int d = 1; d < 16; d <<= 1) tv = fmaxf(tv, __shfl_xor(tv, d, 64));
            if (l16 == 0 && row < MROWS) {
                partials[(size_t)row * NBLK + nb2] = make_float2(mx, sum);
                if (tv > -5e29f) tgtlog[row] = tv;
            }
        }
    }
}

// ---- combine per-block partials -> nll per row; one wave per row ----
__global__ __launch_bounds__(64) void nll_reduce(const float2* __restrict__ partials,
                                                 const float* __restrict__ tgtlog,
                                                 float* __restrict__ nll) {
    int row = blockIdx.x;
    int lane = threadIdx.x;
    float2 loc[3];
    int cnt = 0;
    float m = -1e30f;
    for (int i = lane; i < NBLK; i += 64) {
        float2 p = partials[(size_t)row * NBLK + i];
        loc[cnt++] = p;
        m = fmaxf(m, p.x);
    }
#pragma unroll
    for (int d = 1; d < 64; d <<= 1) m = fmaxf(m, __shfl_xor(m, d, 64));
    float s = 0.f;
    for (int jj = 0; jj < cnt; ++jj) s += loc[jj].y * expf(loc[jj].x - m);
#pragma unroll
    for (int d = 1; d < 64; d <<= 1) s += __shfl_xor(s, d, 64);
    if (lane == 0) nll[row] = -(tgtlog[row] - m - logf(s));
}

__global__ __launch_bounds__(256) void loss_kernel(const float* __restrict__ nll,
                                                   float* __restrict__ out) {
    __shared__ float red[256];
    int tid = threadIdx.x;
    float s = 0.f;
    for (int i = tid; i < TT * BB; i += 256) s += nll[i];
    red[tid] = s; __syncthreads();
    for (int st = 128; st > 0; st >>= 1) { if (tid < st) red[tid] += red[tid + st]; __syncthreads(); }
    if (tid == 0) out[0] = red[0] / (float)BB;
}

extern "C" void kernel_launch(void* const* d_in, const int* in_sizes, int n_in,
                              void* d_out, int out_size, void* d_ws, size_t ws_size,
                              hipStream_t stream) {
    const int*   x   = (const int*)d_in[0];
    const int*   y   = (const int*)d_in[1];
    const float* emb = (const float*)d_in[2];
    const float* W0  = (const float*)d_in[3];
    const float* b0  = (const float*)d_in[4];
    const float* W1  = (const float*)d_in[5];
    const float* b1  = (const float*)d_in[6];
    const float* sw  = (const float*)d_in[7];
    const float* sb  = (const float*)d_in[8];
    float* out = (float*)d_out;

    // ---- workspace layout (~153 MB) ----
    char* p = (char*)d_ws;
    unsigned short* Ae   = (unsigned short*)p; p += (size_t)MPAD * KH * 2;      //  7,077,888
    unsigned short* A1   = (unsigned short*)p; p += (size_t)2 * BB * KT * 2;    //    786,432
    unsigned short* H0   = (unsigned short*)p; p += (size_t)2 * BB * KH * 2;    //    393,216
    unsigned short* outs = (unsigned short*)p; p += (size_t)MPAD * KLP * 2;     //  6,930,432
    float* c0 = (float*)p; p += (size_t)BB * HID * 4;
    float* c1 = (float*)p; p += (size_t)BB * HID * 4;
    float* zpart = (float*)p; p += (size_t)94 * 2 * 4096 * 4;                   //  3,080,192
    int*   zflag = (int*)p;  p += 256 * 4;
    size_t zero_bytes = (size_t)(p - (char*)d_ws);                              // ~22 MB
    unsigned short* Zx   = (unsigned short*)p; p += (size_t)MPAD * ZXN * 2;     // 27,648,000
    unsigned short* WxT0 = (unsigned short*)p; p += (size_t)6000 * KH * 2;      // 18,432,000
    unsigned short* WhT0 = (unsigned short*)p; p += (size_t)6000 * KH * 2;      // 18,432,000
    unsigned short* WbT1 = (unsigned short*)p; p += (size_t)6000 * KT * 2;      // 36,864,000
    unsigned short* swT  = (unsigned short*)p; p += (size_t)VOCAB * KLP * 2;    // 30,080,000
    float2* partials = (float2*)p; p += (size_t)TT * BB * NBLK * 8;             //  2,831,360
    float* tgtlog = (float*)p; p += (size_t)TT * BB * 4;
    float* nll    = (float*)p;

    hipMemsetAsync(d_ws, 0, zero_bytes, stream);

    dim3 cblk(32, 8);
    convT<<<dim3(188, 48), cblk, 0, stream>>>(W0, WxT0, 1500, 6000, KH);
    convT<<<dim3(188, 48), cblk, 0, stream>>>(W0 + (size_t)1500 * 6000, WhT0, 1500, 6000, KH);
    convT<<<dim3(188, 96), cblk, 0, stream>>>(W1, WbT1, 3000, 6000, KT);
    convT<<<dim3(313, 47), cblk, 0, stream>>>(sw, swT, HID, VOCAB, KLP);

    embed_kernel<<<TT * BB, 256, 0, stream>>>(x, emb, Ae);
    zx_gemm<<<864, 256, 0, stream>>>(Ae, WxT0, Zx);

    // launch k: layer0-h[k] on A-blocks + layer1[k-1] split across A/B blocks.
    for (int k = 0; k <= TT; ++k) {
        const unsigned short* A0t = (k < TT) ? H0 + (size_t)((k - 1) & 1) * BB * KH : nullptr;
        unsigned short* d1_0 = A1 + (size_t)(k & 1) * BB * KT;                  // h0[k] for layer1[k]
        unsigned short* d2_0 = H0 + (size_t)(k & 1) * BB * KH;                  // h0[k] for layer0[k+1]
        const unsigned short* zx0 = Zx + (size_t)k * BB * ZXN;

        const unsigned short* A1t = (k >= 1) ? A1 + (size_t)((k - 1) & 1) * BB * KT : nullptr;
        unsigned short* d1_1 = A1 + (size_t)(k & 1) * BB * KT + HID;
        unsigned short* d2_1 = (k >= 1) ? outs + (size_t)(k - 1) * BB * KLP : nullptr;

        lstm_pair<<<188, 1024, 0, stream>>>(A0t, WhT0, b0, c0, d1_0, KT, d2_0, KH, zx0,
                                            A1t, WbT1, b1, c1, d1_1, KT, d2_1, KLP,
                                            zpart, zflag);
    }

    logits_fold<<<1440, 256, 0, stream>>>(outs, swT, sb, y, partials, tgtlog);
    nll_reduce<<<TT * BB, 64, 0, stream>>>(partials, tgtlog, nll);
    loss_kernel<<<1, 256, 0, stream>>>(nll, out);
}

// Round 7
// 1260.798 us; speedup vs baseline: 3.6360x; 3.6360x over previous
//
#include <hip/hip_runtime.h>
#include <math.h>

#define TT 35
#define BB 64
#define EMB 1500
#define HID 1500
#define VOCAB 10000
#define KT 3072          // EMB+HID padded to x128 (4 k-groups x 24 chunks x 32)
#define KG 768           // K per k-group
#define NCH 24           // chunks of 32 per k-group
#define KLP 1504         // HID padded to x32 (logits K)
#define NBLK 158         // vocab 64-col blocks (79 tiles x 2 halves)
#define MROWS 2240       // T*B rows
#define MPAD 2304        // padded to 18*128
#define LBLK 94          // column-blocks per LSTM layer
#define FORGET_BIAS 1.0f

typedef __bf16 bf16x8 __attribute__((ext_vector_type(8)));
typedef float f32x4 __attribute__((ext_vector_type(4)));

__device__ __forceinline__ unsigned short f2bf(float f) {
    unsigned int u = __builtin_bit_cast(unsigned int, f);
    u += 0x7fffu + ((u >> 16) & 1u);           // RNE
    return (unsigned short)(u >> 16);
}
__device__ __forceinline__ float sigmoidf_(float x) { return 1.0f / (1.0f + expf(-x)); }

#define GLOAD_LDS16(gp, lp) __builtin_amdgcn_global_load_lds( \
    (const __attribute__((address_space(1))) void*)(gp),      \
    (__attribute__((address_space(3))) void*)(lp), 16, 0, 0)

// ---- W (K x N fp32) -> WT (N x KP bf16), zero-fill k in [K,KP) ----
__global__ __launch_bounds__(256) void convT(const float* __restrict__ W,
                                             unsigned short* __restrict__ WT,
                                             int K, int N, int KP) {
    __shared__ float tile[32][33];
    int tx = threadIdx.x, ty = threadIdx.y;    // 32 x 8
    int n0 = blockIdx.x * 32, k0 = blockIdx.y * 32;
#pragma unroll
    for (int i = 0; i < 4; ++i) {
        int k = k0 + ty + 8 * i, n = n0 + tx;
        tile[ty + 8 * i][tx] = (k < K && n < N) ? W[(size_t)k * N + n] : 0.f;
    }
    __syncthreads();
#pragma unroll
    for (int i = 0; i < 4; ++i) {
        int n = n0 + ty + 8 * i, k = k0 + tx;
        if (n < N) WT[(size_t)n * KP + k] = f2bf(tile[tx][ty + 8 * i]);
    }
}

// ---- embedding gather -> bf16 into per-step A0 buffers (cols 0..1499) ----
__global__ __launch_bounds__(256) void embed_kernel(const int* __restrict__ x,
                                                    const float* __restrict__ emb,
                                                    unsigned short* __restrict__ A0) {
    int tok = blockIdx.x;                       // t*BB + b (t-major)
    int v = x[tok];
    const float* src = emb + (size_t)v * EMB;
    unsigned short* dst = A0 + (size_t)tok * KT;
    for (int i = threadIdx.x; i < EMB; i += 256) dst[i] = f2bf(src[i]);
}

// ---- fused LSTM pair step: layer0[k] (blocks 0..93) || layer1[k-1] (94..187).
// Proven round-4 structure: 4-buffer depth-3 global_load_lds pipeline with
// counted vmcnt; one raw s_barrier per chunk, no drain in loop. Round-7: the
// LDS swizzle gains the ^((rr>>2)&3) / ^((l16>>2)&3) term (stage & read sides,
// same involution — verified in r6) to remove the residual 4-way read conflict.
// NO split-K, NO fences (r6 lesson: device-scope fences stall ~4-6x).
__global__ __launch_bounds__(1024) void lstm_pair(
        const unsigned short* __restrict__ A_0, const unsigned short* __restrict__ WT_0,
        const float* __restrict__ bias_0, float* __restrict__ cst_0,
        unsigned short* __restrict__ d1_0, int s1_0, unsigned short* __restrict__ d2_0, int s2_0,
        const unsigned short* __restrict__ A_1, const unsigned short* __restrict__ WT_1,
        const float* __restrict__ bias_1, float* __restrict__ cst_1,
        unsigned short* __restrict__ d1_1, int s1_1, unsigned short* __restrict__ d2_1, int s2_1) {
    __shared__ __align__(16) unsigned char smem[131072];

    const unsigned short* A;  const unsigned short* WT;
    const float* bias;        float* cst;
    unsigned short* d1; int s1; unsigned short* d2; int s2;
    int nb;
    if (blockIdx.x < LBLK) {
        if (!A_0) return;
        A = A_0; WT = WT_0; bias = bias_0; cst = cst_0;
        d1 = d1_0; s1 = s1_0; d2 = d2_0; s2 = s2_0;
        nb = blockIdx.x;
    } else {
        if (!A_1) return;
        A = A_1; WT = WT_1; bias = bias_1; cst = cst_1;
        d1 = d1_1; s1 = s1_1; d2 = d2_1; s2 = s2_1;
        nb = blockIdx.x - LBLK;
    }

    int tid = threadIdx.x;
    int wv = tid >> 6, lane = tid & 63;
    int mt = wv & 3, kg = wv >> 2;
    int quad = lane >> 4, l16 = lane & 15;
    int col = nb * 16 + l16;

    int rr = lane >> 2, p = lane & 3;
    int sp = p ^ (rr & 3) ^ ((rr >> 2) & 3);    // XOR swizzle on the GLOBAL side
    int kbase = kg * KG;
    int q0 = mt * 2, q1 = q0 + 1;
    const unsigned short* gp[2];
    int ldsoff[2];
#pragma unroll
    for (int ii = 0; ii < 2; ++ii) {
        int q = ii ? q1 : q0;
        if (q < 4) {                            // A rows 16q+rr
            gp[ii] = A + (size_t)(16 * q + rr) * KT + kbase + sp * 8;
        } else {                                // B: gate g=q-4, col index rr
            int g = q - 4;
            int ci = nb * 16 + rr; if (ci > HID - 1) ci = HID - 1;   // clamp pad cols
            gp[ii] = WT + (size_t)(g * HID + ci) * KT + kbase + sp * 8;
        }
        ldsoff[ii] = ((q >> 2) * 4 + kg) * 4096 + (q & 3) * 1024;    // + buf*32768
    }

    int swz = (quad ^ (l16 & 3) ^ ((l16 >> 2) & 3)) * 16;   // matching read swizzle
    int aoff = (0 * 4 + kg) * 4096 + (mt * 16 + l16) * 64 + swz;     // + buf*32768
    int boff = (1 * 4 + kg) * 4096 + l16 * 64 + swz;                 // + gate*1024 + buf*32768

    f32x4 acc0 = {0.f,0.f,0.f,0.f}, acc1 = acc0, acc2 = acc0, acc3 = acc0;

    // prologue: stage chunks 0..2 into bufs 0..2 (6 loads/wave in flight)
#pragma unroll
    for (int ci = 0; ci < 3; ++ci) {
        GLOAD_LDS16(gp[0] + ci * 32, smem + ci * 32768 + ldsoff[0]);
        GLOAD_LDS16(gp[1] + ci * 32, smem + ci * 32768 + ldsoff[1]);
    }

    for (int c = 0; c < NCH; ++c) {
        asm volatile("s_waitcnt vmcnt(4)" ::: "memory");   // my stage(c) landed
        __builtin_amdgcn_sched_barrier(0);
        __builtin_amdgcn_s_barrier();           // all waves' stage(c) visible
        int cs = (c + 3 < NCH) ? (c + 3) : (NCH - 1);      // dummy tail re-stage
        int bs_ = (c + 3) & 3;
        GLOAD_LDS16(gp[0] + cs * 32, smem + bs_ * 32768 + ldsoff[0]);
        GLOAD_LDS16(gp[1] + cs * 32, smem + bs_ * 32768 + ldsoff[1]);
        const unsigned char* base = smem + (c & 3) * 32768;
        bf16x8 a  = *(const bf16x8*)(base + aoff);
        bf16x8 b0 = *(const bf16x8*)(base + boff);
        bf16x8 b1 = *(const bf16x8*)(base + boff + 1024);
        bf16x8 b2 = *(const bf16x8*)(base + boff + 2048);
        bf16x8 b3 = *(const bf16x8*)(base + boff + 3072);
        __builtin_amdgcn_s_setprio(1);
        acc0 = __builtin_amdgcn_mfma_f32_16x16x32_bf16(a, b0, acc0, 0, 0, 0);
        acc1 = __builtin_amdgcn_mfma_f32_16x16x32_bf16(a, b1, acc1, 0, 0, 0);
        acc2 = __builtin_amdgcn_mfma_f32_16x16x32_bf16(a, b2, acc2, 0, 0, 0);
        acc3 = __builtin_amdgcn_mfma_f32_16x16x32_bf16(a, b3, acc3, 0, 0, 0);
        __builtin_amdgcn_s_setprio(0);
    }
    // drain all in-flight stages before reusing smem for the reduction
    asm volatile("s_waitcnt vmcnt(0)" ::: "memory");
    __builtin_amdgcn_sched_barrier(0);
    __syncthreads();

    float* red = (float*)smem;                  // [12 waves][64 lanes][16]
    if (kg > 0) {
        int w = (kg - 1) * 4 + mt;
#pragma unroll
        for (int r = 0; r < 4; ++r) {
            red[(w * 64 + lane) * 16 + r]      = acc0[r];
            red[(w * 64 + lane) * 16 + 4 + r]  = acc1[r];
            red[(w * 64 + lane) * 16 + 8 + r]  = acc2[r];
            red[(w * 64 + lane) * 16 + 12 + r] = acc3[r];
        }
    }
    __syncthreads();
    if (kg == 0) {
#pragma unroll
        for (int k2 = 0; k2 < 3; ++k2) {
            int w = k2 * 4 + mt;
#pragma unroll
            for (int r = 0; r < 4; ++r) {
                acc0[r] += red[(w * 64 + lane) * 16 + r];
                acc1[r] += red[(w * 64 + lane) * 16 + 4 + r];
                acc2[r] += red[(w * 64 + lane) * 16 + 8 + r];
                acc3[r] += red[(w * 64 + lane) * 16 + 12 + r];
            }
        }
        if (col < HID) {
            float bi = bias[col], bj = bias[HID + col];
            float bf_ = bias[2 * HID + col], bo = bias[3 * HID + col];
#pragma unroll
            for (int r = 0; r < 4; ++r) {
                int row = mt * 16 + quad * 4 + r;
                float zi = acc0[r] + bi;
                float zj = acc1[r] + bj;
                float zf = acc2[r] + bf_;
                float zo = acc3[r] + bo;
                int ci = row * HID + col;
                float cn = cst[ci] * sigmoidf_(zf + FORGET_BIAS) + sigmoidf_(zi) * tanhf(zj);
                float hn = tanhf(cn) * sigmoidf_(zo);
                cst[ci] = cn;
                unsigned short hb = f2bf(hn);
                d1[(size_t)row * s1 + col] = hb;
                if (d2) d2[(size_t)row * s2 + col] = hb;
            }
        }
    }
}

// ---- logits + flash fold; rectangle XCD partition + counted-vmcnt pipeline
// ---- (round-6 version, verified absmax 0; fence-free, block-independent) ----
__global__ __launch_bounds__(256) void logits_fold(const unsigned short* __restrict__ A,   // MPAD x KLP
                                                   const unsigned short* __restrict__ WT,  // 10000 x KLP
                                                   const float* __restrict__ sb,
                                                   const int* __restrict__ y,
                                                   float2* __restrict__ partials,          // [2240][NBLK]
                                                   float* __restrict__ tgtlog) {           // [2240]
    __shared__ __align__(16) unsigned char smem[65536];

    int orig = blockIdx.x;
    int xcd = orig & 7, j = orig >> 3;          // j < 180
    int mb, bn;
    if (xcd < 7) { bn = xcd * 10 + j % 10; mb = j / 10; }
    else { if (j >= 162) return; bn = 70 + j % 9; mb = j / 9; }
    int n0 = bn * 128;

    int tid = threadIdx.x;
    int wv = tid >> 6, lane = tid & 63;
    int wr = wv >> 1, wc = wv & 1;
    int quad = lane >> 4, l16 = lane & 15;

    int rr = lane >> 2;
    int ks = (lane & 3) ^ (rr & 3) ^ ((rr >> 2) & 3);
    const unsigned short* gA[2]; const unsigned short* gB[2];
    int ldsA[2], ldsB[2];
#pragma unroll
    for (int i = 0; i < 2; ++i) {
        int r16 = wv * 2 + i;
        int ra = mb * 128 + r16 * 16 + rr;
        gA[i] = A + (size_t)ra * KLP + ks * 8;
        ldsA[i] = r16 * 1024;
        int rb = n0 + r16 * 16 + rr;
        if (rb > VOCAB - 1) rb = VOCAB - 1;
        gB[i] = WT + (size_t)rb * KLP + ks * 8;
        ldsB[i] = 8192 + r16 * 1024;
    }

    int sw16 = (quad ^ (l16 & 3) ^ ((l16 >> 2) & 3)) * 16;
    int aoff[4], boff[4];
#pragma unroll
    for (int f = 0; f < 4; ++f) {
        aoff[f] = (wr * 64 + f * 16 + l16) * 64 + sw16;
        boff[f] = 8192 + (wc * 64 + f * 16 + l16) * 64 + sw16;
    }

    f32x4 acc[4][4];
#pragma unroll
    for (int i = 0; i < 4; ++i)
#pragma unroll
        for (int jj = 0; jj < 4; ++jj) acc[i][jj] = (f32x4){0.f, 0.f, 0.f, 0.f};

    const int NCHL = KLP / 32;                  // 47
#pragma unroll
    for (int ci = 0; ci < 3; ++ci)
#pragma unroll
        for (int i = 0; i < 2; ++i) {
            GLOAD_LDS16(gA[i] + ci * 32, smem + ci * 16384 + ldsA[i]);
            GLOAD_LDS16(gB[i] + ci * 32, smem + ci * 16384 + ldsB[i]);
        }
    for (int c = 0; c < NCHL; ++c) {
        asm volatile("s_waitcnt vmcnt(8)" ::: "memory");
        __builtin_amdgcn_sched_barrier(0);
        __builtin_amdgcn_s_barrier();
        int cs = (c + 3 < NCHL) ? (c + 3) : (NCHL - 1);
        int ob = ((c + 3) & 3) * 16384;
#pragma unroll
        for (int i = 0; i < 2; ++i) {
            GLOAD_LDS16(gA[i] + cs * 32, smem + ob + ldsA[i]);
            GLOAD_LDS16(gB[i] + cs * 32, smem + ob + ldsB[i]);
        }
        const unsigned char* base = smem + (c & 3) * 16384;
        bf16x8 a[4], b[4];
#pragma unroll
        for (int f = 0; f < 4; ++f) {
            a[f] = *(const bf16x8*)(base + aoff[f]);
            b[f] = *(const bf16x8*)(base + boff[f]);
        }
        __builtin_amdgcn_s_setprio(1);
#pragma unroll
        for (int ar = 0; ar < 4; ++ar)
#pragma unroll
            for (int cbv = 0; cbv < 4; ++cbv)
                acc[ar][cbv] = __builtin_amdgcn_mfma_f32_16x16x32_bf16(a[ar], b[cbv], acc[ar][cbv], 0, 0, 0);
        __builtin_amdgcn_s_setprio(0);
    }
    asm volatile("s_waitcnt vmcnt(0)" ::: "memory");
    __builtin_amdgcn_sched_barrier(0);
    __syncthreads();

    int colv[4]; float bs[4];
#pragma unroll
    for (int cbv = 0; cbv < 4; ++cbv) {
        int c = n0 + wc * 64 + cbv * 16 + l16;
        colv[cbv] = c;
        int cc = (c < VOCAB) ? c : (VOCAB - 1);
        bs[cbv] = sb[cc];
    }
    int nb2 = bn * 2 + wc;
#pragma unroll
    for (int ar = 0; ar < 4; ++ar) {
#pragma unroll
        for (int r2 = 0; r2 < 4; ++r2) {
            float v0 = acc[ar][0][r2] + bs[0];
            float v1 = acc[ar][1][r2] + bs[1];
            float v2 = acc[ar][2][r2] + bs[2];
            float v3 = acc[ar][3][r2] + bs[3];
            if (colv[0] >= VOCAB) v0 = -1e30f;
            if (colv[1] >= VOCAB) v1 = -1e30f;
            if (colv[2] >= VOCAB) v2 = -1e30f;
            if (colv[3] >= VOCAB) v3 = -1e30f;
            int row = mb * 128 + wr * 64 + ar * 16 + quad * 4 + r2;
            int t = y[row < MROWS ? row : 0];
            float tv = -1e30f;
            if (colv[0] == t) tv = v0;
            if (colv[1] == t) tv = v1;
            if (colv[2] == t) tv = v2;
            if (colv[3] == t) tv = v3;
            float mx = fmaxf(fmaxf(v0, v1), fmaxf(v2, v3));
#pragma unroll
            for (int d = 1; d < 16; d <<= 1) mx = fmaxf(mx, __shfl_xor(mx, d, 64));
            float sum = expf(v0 - mx) + expf(v1 - mx) + expf(v2 - mx) + expf(v3 - mx);
#pragma unroll
            for (int d = 1; d < 16; d <<= 1) sum += __shfl_xor(sum, d, 64);
#pragma unroll
            for (int d = 1; d < 16; d <<= 1) tv = fmaxf(tv, __shfl_xor(tv, d, 64));
            if (l16 == 0 && row < MROWS) {
                partials[(size_t)row * NBLK + nb2] = make_float2(mx, sum);
                if (tv > -5e29f) tgtlog[row] = tv;
            }
        }
    }
}

// ---- combine per-block partials -> nll per row; one wave per row ----
__global__ __launch_bounds__(64) void nll_reduce(const float2* __restrict__ partials,
                                                 const float* __restrict__ tgtlog,
                                                 float* __restrict__ nll) {
    int row = blockIdx.x;
    int lane = threadIdx.x;
    float2 loc[3];
    int cnt = 0;
    float m = -1e30f;
    for (int i = lane; i < NBLK; i += 64) {
        float2 p = partials[(size_t)row * NBLK + i];
        loc[cnt++] = p;
        m = fmaxf(m, p.x);
    }
#pragma unroll
    for (int d = 1; d < 64; d <<= 1) m = fmaxf(m, __shfl_xor(m, d, 64));
    float s = 0.f;
    for (int jj = 0; jj < cnt; ++jj) s += loc[jj].y * expf(loc[jj].x - m);
#pragma unroll
    for (int d = 1; d < 64; d <<= 1) s += __shfl_xor(s, d, 64);
    if (lane == 0) nll[row] = -(tgtlog[row] - m - logf(s));
}

__global__ __launch_bounds__(256) void loss_kernel(const float* __restrict__ nll,
                                                   float* __restrict__ out) {
    __shared__ float red[256];
    int tid = threadIdx.x;
    float s = 0.f;
    for (int i = tid; i < TT * BB; i += 256) s += nll[i];
    red[tid] = s; __syncthreads();
    for (int st = 128; st > 0; st >>= 1) { if (tid < st) red[tid] += red[tid + st]; __syncthreads(); }
    if (tid == 0) out[0] = red[0] / (float)BB;
}

extern "C" void kernel_launch(void* const* d_in, const int* in_sizes, int n_in,
                              void* d_out, int out_size, void* d_ws, size_t ws_size,
                              hipStream_t stream) {
    const int*   x   = (const int*)d_in[0];
    const int*   y   = (const int*)d_in[1];
    const float* emb = (const float*)d_in[2];
    const float* W0  = (const float*)d_in[3];
    const float* b0  = (const float*)d_in[4];
    const float* W1  = (const float*)d_in[5];
    const float* b1  = (const float*)d_in[6];
    const float* sw  = (const float*)d_in[7];
    const float* sb  = (const float*)d_in[8];
    float* out = (float*)d_out;

    // ---- workspace layout (round-4 proven) ----
    char* p = (char*)d_ws;
    unsigned short* A0   = (unsigned short*)p; p += (size_t)TT * BB * KT * 2;   // 13,762,560
    unsigned short* A1   = (unsigned short*)p; p += (size_t)2 * BB * KT * 2;    //    786,432
    unsigned short* outs = (unsigned short*)p; p += (size_t)MPAD * KLP * 2;     //  6,930,432 (rows 2240..2303 stay zero)
    float* c0 = (float*)p; p += (size_t)BB * HID * 4;
    float* c1 = (float*)p; p += (size_t)BB * HID * 4;
    size_t zero_bytes = (size_t)(p - (char*)d_ws);
    unsigned short* WbT0 = (unsigned short*)p; p += (size_t)6000 * KT * 2;      // 36,864,000
    unsigned short* WbT1 = (unsigned short*)p; p += (size_t)6000 * KT * 2;      // 36,864,000
    unsigned short* swT  = (unsigned short*)p; p += (size_t)VOCAB * KLP * 2;    // 30,080,000
    float2* partials = (float2*)p; p += (size_t)TT * BB * NBLK * 8;             //  2,831,360
    float* tgtlog = (float*)p; p += (size_t)TT * BB * 4;
    float* nll    = (float*)p;

    hipMemsetAsync(d_ws, 0, zero_bytes, stream);

    dim3 cblk(32, 8);
    convT<<<dim3(188, 96), cblk, 0, stream>>>(W0, WbT0, 3000, 6000, KT);
    convT<<<dim3(188, 96), cblk, 0, stream>>>(W1, WbT1, 3000, 6000, KT);
    convT<<<dim3(313, 47), cblk, 0, stream>>>(sw, swT, HID, VOCAB, KLP);

    embed_kernel<<<TT * BB, 256, 0, stream>>>(x, emb, A0);

    // software pipeline: launch k runs layer0[k] (blocks 0..93) and layer1[k-1]
    // (blocks 94..187) concurrently. 36 launches, 188 CUs busy.
    for (int k = 0; k <= TT; ++k) {
        const unsigned short* A0t = (k < TT) ? A0 + (size_t)k * BB * KT : nullptr;
        unsigned short* d1_0 = A1 + (size_t)(k & 1) * BB * KT;
        unsigned short* d2_0 = (k < TT - 1) ? (A0 + (size_t)(k + 1) * BB * KT + EMB) : nullptr;

        const unsigned short* A1t = (k >= 1) ? A1 + (size_t)((k - 1) & 1) * BB * KT : nullptr;
        unsigned short* d1_1 = A1 + (size_t)(k & 1) * BB * KT + HID;
        unsigned short* d2_1 = (k >= 1) ? outs + (size_t)(k - 1) * BB * KLP : nullptr;

        lstm_pair<<<188, 1024, 0, stream>>>(A0t, WbT0, b0, c0, d1_0, KT, d2_0, KT,
                                            A1t, WbT1, b1, c1, d1_1, KT, d2_1, KLP);
    }

    logits_fold<<<1440, 256, 0, stream>>>(outs, swT, sb, y, partials, tgtlog);
    nll_reduce<<<TT * BB, 64, 0, stream>>>(partials, tgtlog, nll);
    loss_kernel<<<1, 256, 0, stream>>>(nll, out);
}